// Round 1
// 1313.790 us; speedup vs baseline: 1.0501x; 1.0501x over previous
//
#include <hip/hip_runtime.h>
#include <hip/hip_fp16.h>
#include <math.h>

#define Bsz 128
#define Tsz 512
#define Hsz 1024
#define NM  8
#define MS  128
#define NT  512
#define NPAIR 36

// ws layout: [0, 64KB) WB0: fp32 block (0,0), j-fastest [row*128+j]
//            [64KB, +1.09MB) WBh: half blocks p=1..35, layout [j*128+row]

// ---------------------------------------------------------------------------
__global__ __launch_bounds__(256)
void retile_whh(const float* __restrict__ W, float* __restrict__ WB0,
                __half* __restrict__ WBh) {
    __shared__ float tile[MS][MS + 1];
    const int p = blockIdx.x;
    const int t = threadIdx.x;
    if (p == 0) {
        for (int idx = t; idx < MS * MS; idx += 256) {
            const int row = idx >> 7, j = idx & (MS - 1);
            WB0[idx] = W[row * Hsz + j];
        }
        return;
    }
    int c = 0;
    while ((c + 1) * (c + 2) / 2 <= p) ++c;
    const int r = p - c * (c + 1) / 2;
    for (int idx = t; idx < MS * MS; idx += 256) {
        const int row = idx >> 7, j = idx & (MS - 1);
        tile[row][j] = W[(size_t)(r * MS + row) * Hsz + c * MS + j];
    }
    __syncthreads();
    __half* wb = WBh + (size_t)(p - 1) * MS * MS;
    for (int idx = t; idx < MS * MS; idx += 256) {
        const int j = idx >> 7, row = idx & (MS - 1);
        wb[idx] = __float2half(tile[row][j]);
    }
}

__device__ __forceinline__ float fast_tanh(float x) {
    const float e = __expf(2.0f * x);
    return 1.0f - 2.0f * __builtin_amdgcn_rcpf(e + 1.0f);
}

// DPP fetch: returns neighbor lane's value per CTRL (0 for invalid lanes).
template <int CTRL>
__device__ __forceinline__ float dpp_get(float v) {
    union { float f; int i; } u, o;
    u.f = v;
    o.i = __builtin_amdgcn_update_dpp(0, u.i, CTRL, 0xf, 0xf, true);
    return o.f;
}

union H4 { short4 s4; __half2 h2[2]; };

// ---------------------------------------------------------------------------
// Persistent per-batch-element Clockwork RNN. grid=128, block=512 (8 waves).
// 2 barriers/step. Changes vs R4-polish:
//  * P1 recurrent sum: compile-time-unrolled masked gather (16 parallel
//    ds_reads, one latency) instead of runtime-trip serialized loop.
//  * fc output: per-module persistent partials (Opart) fused into P1 via
//    VALU DPP wave-reduction; tid0 finalizes + stores to global in phase 2.
//    (full-width P2 + 6-stage ds_bpermute shfl chain removed)
//  * pairs 1..5 (cols 1,2) cached as packed fp16 in registers (80 VGPR),
//    refreshed refresh00-style; wlds now holds pairs 6,7; stream only p>=8.
// ---------------------------------------------------------------------------
__global__ __launch_bounds__(NT)
void cwrnn_kernel(const float* __restrict__ x,      // [B, T+1, 2, 1]
                  const float* __restrict__ W_ih,   // [H, 2]
                  const float* __restrict__ fc_w,   // [2, H]
                  const float* __restrict__ fc_b,   // [2]
                  const float* __restrict__ enc_w,  // [H, 2]
                  const float* __restrict__ WB0,    // fp32 (0,0)
                  const __half* __restrict__ WBh,   // fp16 pairs 1..35
                  float* __restrict__ out)          // [B, T, 2]
{
    __shared__ __half wlds[2 * MS * MS];  // pairs 6,7 (col 3): 64 KB
    __shared__ float  Sp2[NPAIR][2][MS];  // 36 KB
    __shared__ float  h_s[Hsz];
    __shared__ float2 x_s[Tsz + 1];
    __shared__ float2 wih_s[Hsz];
    __shared__ float2 fcw_s[Hsz];
    __shared__ float2 Opart[16];          // per-half-module fc partials, persist

    const int tid = threadIdx.x;
    const int b   = blockIdx.x;

    const float2* xb = (const float2*)(x + (size_t)b * (Tsz + 1) * 2);
    float* outb = out + (size_t)b * Tsz * 2;

    for (int i = tid; i < Tsz + 1; i += NT) x_s[i] = xb[i];
    for (int i = tid; i < Hsz; i += NT) wih_s[i] = ((const float2*)W_ih)[i];
    for (int i = tid; i < Hsz; i += NT)
        fcw_s[i] = make_float2(fc_w[i], fc_w[Hsz + i]);
    for (int i = tid; i < 2 * MS * MS / 4; i += NT)
        ((short4*)wlds)[i] = ((const short4*)(WBh + 5 * MS * MS))[i]; // pairs 6,7
    const float fb0 = fc_b[0], fb1 = fc_b[1];

    // ---- (0,0) fp32 register cache: row00=tid>>2, jc=tid&3 (rotated) ----
    const int row00 = tid >> 2;
    const int jc    = tid & 3;
    float4 w00[8];
    #pragma unroll
    for (int u = 0; u < 8; ++u) {
        const int uu = (u + 2 * jc) & 7;
        w00[u] = *(const float4*)(WB0 + row00 * MS + jc * 32 + uu * 4);
    }

    // ---- fp16 register cache: pairs 1,2 (col 1), 3,4,5 (col 2) ----
    short4 wreg1[8], wreg2[8], wreg3[8], wreg4[8], wreg5[8];
    {
        const ushort* WBu = (const ushort*)WBh;
#define LOAD_WREG(K)                                                       \
        _Pragma("unroll")                                                  \
        for (int u = 0; u < 8; ++u) {                                      \
            const int uu = (u + 2 * jc) & 7;                               \
            const int j0 = jc * 32 + uu * 4;                               \
            const size_t base = (size_t)((K) - 1) * MS * MS + row00;       \
            short4 w;                                                      \
            w.x = (short)WBu[base + (size_t)(j0 + 0) * MS];                \
            w.y = (short)WBu[base + (size_t)(j0 + 1) * MS];                \
            w.z = (short)WBu[base + (size_t)(j0 + 2) * MS];                \
            w.w = (short)WBu[base + (size_t)(j0 + 3) * MS];                \
            wreg##K[u] = w;                                                \
        }
        LOAD_WREG(1) LOAD_WREG(2) LOAD_WREG(3) LOAD_WREG(4) LOAD_WREG(5)
    }

    // ---- refresh_hi mapping (coalesced) ----
    const int slot = tid >> 7;            // pair slot 0..3
    const int s    = tid & 127;
    const int row4 = (s & 31) * 4;
    const int jq   = s >> 5;
    const int part = (tid >> 6) & 1;
    const bool wr_gate = ((tid >> 5) & 1) == 0;

    // ---- h0 = x[:,0] @ enc_w.T ----
    {
        const float2 x0 = xb[0];
        for (int i = tid; i < Hsz; i += NT) {
            const float2 ew = ((const float2*)enc_w)[i];
            h_s[i] = x0.x * ew.x + x0.y * ew.y;
        }
    }
    __syncthreads();

    auto refresh00 = [&]() {
        float a = 0.f;
        #pragma unroll
        for (int u = 0; u < 8; ++u) {
            const int uu = (u + 2 * jc) & 7;
            const float4 hv = *(const float4*)(h_s + jc * 32 + uu * 4);
            a += w00[u].x * hv.x + w00[u].y * hv.y + w00[u].z * hv.z + w00[u].w * hv.w;
        }
        a += dpp_get<0xB1>(a);            // + lane^1 (quad_perm [1,0,3,2])
        if (jc == 0)      Sp2[0][0][row00] = a;
        else if (jc == 2) Sp2[0][1][row00] = a;
    };

#define REFRESH_REG(K, P_, C_)                                             \
    {                                                                      \
        float a = 0.f;                                                     \
        _Pragma("unroll")                                                  \
        for (int u = 0; u < 8; ++u) {                                      \
            const int uu = (u + 2 * jc) & 7;                               \
            const float4 hv = *(const float4*)(h_s + (C_) * MS + jc * 32 + uu * 4); \
            H4 w; w.s4 = wreg##K[u];                                       \
            const float2 f01 = __half22float2(w.h2[0]);                    \
            const float2 f23 = __half22float2(w.h2[1]);                    \
            a += f01.x * hv.x + f01.y * hv.y + f23.x * hv.z + f23.y * hv.w; \
        }                                                                  \
        a += dpp_get<0xB1>(a);                                             \
        if (jc == 0)      Sp2[P_][0][row00] = a;                           \
        else if (jc == 2) Sp2[P_][1][row00] = a;                           \
    }

    auto pair_body = [&](const __half* __restrict__ wsrc, int c) -> float4 {
        const float* hc = h_s + c * MS;
        const __half* wp = wsrc + (size_t)(jq * 32) * MS + row4;
        float4 acc = {0.f, 0.f, 0.f, 0.f};
        #pragma unroll 8
        for (int jj = 0; jj < 32; ++jj) {
            const float hj = hc[jq * 32 + jj];
            H4 u; u.s4 = *(const short4*)(wp + (size_t)jj * MS);
            const float2 f01 = __half22float2(u.h2[0]);
            const float2 f23 = __half22float2(u.h2[1]);
            acc.x += f01.x * hj; acc.y += f01.y * hj;
            acc.z += f23.x * hj; acc.w += f23.y * hj;
        }
        return acc;
    };

    auto do_pair = [&](int p, int c) {
        float4 acc;
        if (p <= 7) acc = pair_body(wlds + (size_t)(p - 6) * MS * MS, c);
        else        acc = pair_body(WBh  + (size_t)(p - 1) * MS * MS, c);
        acc.x += __shfl_xor(acc.x, 32, 64); acc.y += __shfl_xor(acc.y, 32, 64);
        acc.z += __shfl_xor(acc.z, 32, 64); acc.w += __shfl_xor(acc.w, 32, 64);
        if (wr_gate) *(float4*)&Sp2[p][part][row4] = acc;
    };

    auto refresh_hi = [&](int P) {        // pairs 6..P-1 (cols >= 3), 4 concurrent
        for (int pb = 6; pb < P; pb += 4) {
            const int p = pb + slot;
            if (p < P) {
                const int c = 3 + (p >= 10) + (p >= 15) + (p >= 21) + (p >= 28);
                do_pair(p, c);
            }
        }
    };

    refresh_hi(NPAIR);                    // streams issued first
    refresh00();
    REFRESH_REG(1, 1, 1) REFRESH_REG(2, 2, 1)
    REFRESH_REG(3, 3, 2) REFRESH_REG(4, 4, 2) REFRESH_REG(5, 5, 2)
    __syncthreads();

    for (int t = 0; t < Tsz; ++t) {
        const int A = (t == 0) ? 7 : min(__ffs(t) - 1, 7);
        const int nrows = (A + 1) * MS;
        const float2 xt = x_s[t + 1];

        // ---- P1: candidate + h update + fused fc partials ----
        for (int g = tid; g < nrows; g += NT) {
            const int r  = g >> 7;
            const int il = g & (MS - 1);
            // burst-issue all 16 Sp2 reads (pidx always in [0,36)), mask after
            float sc[8];
            #pragma unroll
            for (int c = 0; c < 8; ++c) {
                const int pidx = c * (c + 1) / 2 + r;
                sc[c] = Sp2[pidx][0][il] + Sp2[pidx][1][il];
            }
            const float2 wih2 = wih_s[g];
            float pre = xt.x * wih2.x + xt.y * wih2.y;
            #pragma unroll
            for (int c = 0; c < 8; ++c) pre += (c >= r) ? sc[c] : 0.0f;
            const float hv = fast_tanh(pre);
            h_s[g] = hv;
            // fc partial for this half-module (wave-wide DPP sum, VALU pipe)
            const float2 fw = fcw_s[g];
            float o0 = hv * fw.x, o1 = hv * fw.y;
            o0 += dpp_get<0x111>(o0); o1 += dpp_get<0x111>(o1);  // row_shr:1
            o0 += dpp_get<0x112>(o0); o1 += dpp_get<0x112>(o1);  // row_shr:2
            o0 += dpp_get<0x114>(o0); o1 += dpp_get<0x114>(o1);  // row_shr:4
            o0 += dpp_get<0x118>(o0); o1 += dpp_get<0x118>(o1);  // row_shr:8
            o0 += dpp_get<0x142>(o0); o1 += dpp_get<0x142>(o1);  // row_bcast:15
            o0 += dpp_get<0x143>(o0); o1 += dpp_get<0x143>(o1);  // row_bcast:31
            if ((tid & 63) == 63) Opart[g >> 6] = make_float2(o0, o1);
        }
        __syncthreads();                  // barrier 1: h_s, Opart ready

        // ---- phase 2: out[t] finalize + Sp2 refresh for cols <= A ----
        if (tid == 0) {
            float o0 = fb0, o1 = fb1;
            #pragma unroll
            for (int k = 0; k < 16; ++k) { o0 += Opart[k].x; o1 += Opart[k].y; }
            *(float2*)(outb + 2 * t) = make_float2(o0, o1);
        }
        refresh_hi((A + 1) * (A + 2) / 2);   // streams issued early
        refresh00();
        if (A >= 1) { REFRESH_REG(1, 1, 1) REFRESH_REG(2, 2, 1) }
        if (A >= 2) { REFRESH_REG(3, 3, 2) REFRESH_REG(4, 4, 2) REFRESH_REG(5, 5, 2) }
        __syncthreads();                  // barrier 2: Sp2 ready, h_s reusable
    }
}

// ---------------------------------------------------------------------------
extern "C" void kernel_launch(void* const* d_in, const int* in_sizes, int n_in,
                              void* d_out, int out_size, void* d_ws, size_t ws_size,
                              hipStream_t stream) {
    const float* x     = (const float*)d_in[0];
    const float* W_ih  = (const float*)d_in[1];
    const float* W_hh  = (const float*)d_in[2];
    const float* fc_w  = (const float*)d_in[3];
    const float* fc_b  = (const float*)d_in[4];
    const float* enc_w = (const float*)d_in[5];
    float* outp = (float*)d_out;
    float*  WB0 = (float*)d_ws;                          // 64 KB
    __half* WBh = (__half*)((char*)d_ws + 65536);        // 35*16384*2 B

    retile_whh<<<NPAIR, 256, 0, stream>>>(W_hh, WB0, WBh);
    cwrnn_kernel<<<Bsz, NT, 0, stream>>>(x, W_ih, fc_w, fc_b, enc_w, WB0, WBh, outp);
}

// Round 2
// 974.655 us; speedup vs baseline: 1.4155x; 1.3480x over previous
//
#include <hip/hip_runtime.h>
#include <hip/hip_fp16.h>
#include <math.h>

#define Bsz 128
#define Tsz 512
#define Hsz 1024
#define MS  128
#define NT  512

// ws layout: [0, 64KB) WB0: fp32 block (0,0), row-major [row*128+j]
//            [64KB, +1.09MB) WBr: fp16 pairs p=1..35, ROW-major [row*128+j]
// pair index p = c*(c+1)/2 + r  (block (r,c), r<=c)

// ---------------------------------------------------------------------------
__global__ __launch_bounds__(256)
void retile_whh(const float* __restrict__ W, float* __restrict__ WB0,
                __half* __restrict__ WBr) {
    const int p = blockIdx.x;
    const int t = threadIdx.x;
    if (p == 0) {
        for (int idx = t; idx < MS*MS; idx += 256) {
            const int row = idx >> 7, j = idx & (MS-1);
            WB0[idx] = W[row * Hsz + j];
        }
        return;
    }
    int c = 0;
    while ((c+1)*(c+2)/2 <= p) ++c;
    const int r = p - c*(c+1)/2;
    __half* wb = WBr + (size_t)(p-1) * MS * MS;
    for (int idx = t; idx < MS*MS; idx += 256) {
        const int row = idx >> 7, j = idx & (MS-1);
        wb[idx] = __float2half(W[(size_t)(r*MS+row)*Hsz + c*MS + j]);
    }
}

__device__ __forceinline__ float fast_tanh(float x) {
    const float e = __expf(2.0f * x);
    return 1.0f - 2.0f * __builtin_amdgcn_rcpf(e + 1.0f);
}

template <int CTRL>
__device__ __forceinline__ float dpp_get(float v) {
    union { float f; int i; } u, o;
    u.f = v;
    o.i = __builtin_amdgcn_update_dpp(0, u.i, CTRL, 0xf, 0xf, true);
    return o.f;
}

union H4 { short4 s4; __half2 h2[2]; };

// ---------------------------------------------------------------------------
// Persistent Clockwork RNN, grid=128, block=512 (8 waves). ONE barrier/step.
//
// Dataflow exploit: col 0 feeds only module 0, so h0 (updates every step)
// never needs Sp2: its diagonal W00*h0 is computed inline in quad layout
// (4 threads/row: row00=tid>>2, jc=tid&3), and its off-diagonal terms
// W(0,c)*hc live as per-thread register quarter-partials R1..R7, refreshed
// in the region after column c updates (no LDS write -> no extra barrier).
// All r>=1 pair refreshes (Sp2s, full sums) have >=2-step slack and run in
// the following ODD region (where P1 touches only the ping-ponged H0).
// fc output: per-wave DPP partials; tid0 finalizes out[t-1] next region.
// ---------------------------------------------------------------------------
__global__ __launch_bounds__(NT)
void cwrnn_kernel(const float* __restrict__ x,      // [B, T+1, 2, 1]
                  const float* __restrict__ W_ih,   // [H, 2]
                  const float* __restrict__ fc_w,   // [2, H]
                  const float* __restrict__ fc_b,   // [2]
                  const float* __restrict__ enc_w,  // [H, 2]
                  const float* __restrict__ WB0,    // fp32 (0,0) row-major
                  const __half* __restrict__ WBr,   // fp16 pairs 1..35 row-major
                  float* __restrict__ out)          // [B, T, 2]
{
    __shared__ __half  WL[3][MS*136];   // pairs (1,1),(1,2),(2,2), pad 136
    __shared__ float   Sp2s[36][MS];    // full row-sums, pairs r>=1 only
    __shared__ float   h_s[Hsz];        // cols 1..7 live here (col 0 in H0)
    __shared__ float   H0[2][MS];       // module-0 state, ping-pong
    __shared__ float2  x_s[Tsz+1];
    __shared__ float2  wih_s[Hsz];
    __shared__ float2  fcw_s[Hsz];
    __shared__ float2  OpM0[2][8];      // module-0 fc partials (dbuf)
    __shared__ float2  OpHi[16];        // promoted hi-module fc partials
    __shared__ float2  OpHiN[16];       // staging (written at even regions)

    const int tid   = threadIdx.x;
    const int lane  = tid & 63;
    const int wave  = tid >> 6;
    const int b     = blockIdx.x;
    const int row00 = tid >> 2;
    const int jc    = tid & 3;

    const float2* xb = (const float2*)(x + (size_t)b*(Tsz+1)*2);
    float* outb = out + (size_t)b*Tsz*2;

    for (int i = tid; i < Tsz+1; i += NT) x_s[i] = xb[i];
    for (int i = tid; i < Hsz; i += NT) wih_s[i] = ((const float2*)W_ih)[i];
    for (int i = tid; i < Hsz; i += NT) fcw_s[i] = make_float2(fc_w[i], fc_w[Hsz+i]);
    // WL staging: pairs p=2,4,5 row-major, padded stride 136 halfs
    for (int q = tid; q < 3*MS*16; q += NT) {
        const int pi = q / (MS*16), rem = q - pi*(MS*16);
        const int row = rem >> 4, k = rem & 15;
        const int p = (pi == 0) ? 2 : 3 + pi;
        *(int4*)(&WL[pi][row*136 + k*8]) =
            *(const int4*)(WBr + (size_t)(p-1)*MS*MS + row*MS + k*8);
    }
    if (tid < 16) { OpHi[tid] = make_float2(0.f,0.f); OpHiN[tid] = make_float2(0.f,0.f); }
    const float fb0 = fc_b[0], fb1 = fc_b[1];

    // W00 fp32 register cache (rotated chunks -> bank-spread h reads)
    float4 w00[8];
    #pragma unroll
    for (int u = 0; u < 8; ++u) {
        const int uu = (u + 2*jc) & 7;
        w00[u] = *(const float4*)(WB0 + row00*MS + jc*32 + uu*4);
    }
    // fp16 register caches: pair 1 = (0,1), pair 3 = (0,2), same rotation
    short4 w01[8], w02[8];
    #pragma unroll
    for (int u = 0; u < 8; ++u) {
        const int uu = (u + 2*jc) & 7;
        w01[u] = *(const short4*)(WBr + (size_t)0*MS*MS + row00*MS + jc*32 + uu*4);
        w02[u] = *(const short4*)(WBr + (size_t)2*MS*MS + row00*MS + jc*32 + uu*4);
    }

    {   // h0 = x[:,0] @ enc_w.T
        const float2 x0 = xb[0];
        for (int i = tid; i < Hsz; i += NT) {
            const float2 ew = ((const float2*)enc_w)[i];
            const float v = x0.x*ew.x + x0.y*ew.y;
            h_s[i] = v;
            if (i < MS) H0[0][i] = v;
        }
    }
    __syncthreads();

    float R1=0.f,R2=0.f,R3=0.f,R4=0.f,R5=0.f,R6=0.f,R7=0.f;

    auto load_hq = [&](int c, float4* hq) {
        #pragma unroll
        for (int u = 0; u < 8; ++u) {
            const int uu = (u + 2*jc) & 7;
            hq[u] = *(const float4*)(h_s + c*MS + jc*32 + uu*4);
        }
    };
    auto pair_acc = [&](const short4* w, const float4* hq) -> float {
        float a = 0.f;
        #pragma unroll
        for (int u = 0; u < 8; ++u) {
            H4 ww; ww.s4 = w[u];
            const float2 f01 = __half22float2(ww.h2[0]);
            const float2 f23 = __half22float2(ww.h2[1]);
            a += f01.x*hq[u].x + f01.y*hq[u].y + f23.x*hq[u].z + f23.y*hq[u].w;
        }
        return a;
    };
    auto wl_load = [&](int idx, short4* w) {
        const __half* base = WL[idx] + row00*136;
        #pragma unroll
        for (int u = 0; u < 8; ++u) {
            const int uu = (u + 2*jc) & 7;
            w[u] = *(const short4*)(base + jc*32 + uu*4);
        }
    };
    auto wg_load = [&](int p, short4* w) {
        const __half* base = WBr + (size_t)(p-1)*MS*MS + row00*MS;
        #pragma unroll
        for (int u = 0; u < 8; ++u) {
            const int uu = (u + 2*jc) & 7;
            w[u] = *(const short4*)(base + jc*32 + uu*4);
        }
    };

    // Refresh all contributions of columns 1..ashad:
    //  r=0 -> register quarter-partials Rc (no reduce, no LDS)
    //  r>=1 -> quad-reduced full sums into Sp2s (read >=2 steps later)
    auto do_cols = [&](int ashad) {
        float4 hq[8];
        short4 wA[8], wB[8];
        if (ashad >= 3) {                // c>=3: weights streamed from L2, depth-2 pipeline
            load_hq(3, hq);
            wg_load(6, wA);              // (0,3)
            int cc = 3, rr = 0;
            while (true) {
                int rn = rr + 1, cn = cc;
                if (rn > cn) { cn += 1; rn = 0; }
                const bool hn = (cn <= ashad);
                if (hn) wg_load(cn*(cn+1)/2 + rn, wB);
                float aa = pair_acc(wA, hq);
                if (rr == 0) {
                    switch (cc) {
                        case 3: R3 = aa; break;
                        case 4: R4 = aa; break;
                        case 5: R5 = aa; break;
                        case 6: R6 = aa; break;
                        default: R7 = aa; break;
                    }
                } else {
                    aa += dpp_get<0xB1>(aa); aa += dpp_get<0x4E>(aa);
                    if (jc == 0) Sp2s[cc*(cc+1)/2 + rr][row00] = aa;
                }
                if (!hn) break;
                if (cn != cc) load_hq(cn, hq);
                cc = cn; rr = rn;
                #pragma unroll
                for (int u = 0; u < 8; ++u) wA[u] = wB[u];
            }
        }
        load_hq(1, hq);
        R1 = pair_acc(w01, hq);
        wl_load(0, wA);
        { float aa = pair_acc(wA, hq);
          aa += dpp_get<0xB1>(aa); aa += dpp_get<0x4E>(aa);
          if (jc == 0) Sp2s[2][row00] = aa; }             // (1,1)
        if (ashad >= 2) {
            load_hq(2, hq);
            R2 = pair_acc(w02, hq);
            wl_load(1, wA);
            { float aa = pair_acc(wA, hq);
              aa += dpp_get<0xB1>(aa); aa += dpp_get<0x4E>(aa);
              if (jc == 0) Sp2s[4][row00] = aa; }         // (1,2)
            wl_load(2, wB);
            { float aa = pair_acc(wB, hq);
              aa += dpp_get<0xB1>(aa); aa += dpp_get<0x4E>(aa);
              if (jc == 0) Sp2s[5][row00] = aa; }         // (2,2)
        }
    };

    do_cols(7);                 // init Sp2s + R1..R7 from encoder state
    __syncthreads();

    for (int t = 0; t < Tsz; ++t) {
        const int A  = (t == 0) ? 7 : ((t & 1) ? 0 : min(__ffs(t)-1, 7));
        const int ap = (t & 1) ? ((t == 1) ? 7 : min(__ffs(t-1)-1, 7)) : 0;
        const float2 xt = x_s[t+1];

        // ---- deferred refresh of cols active at t-1 (odd regions only) ----
        if (ap >= 1) do_cols(ap);

        // ---- module 0: inline diagonal + register off-diagonals ----
        {
            const float* h0r = H0[t & 1];
            float a = 0.f;
            #pragma unroll
            for (int u = 0; u < 8; ++u) {
                const int uu = (u + 2*jc) & 7;
                const float4 hv = *(const float4*)(h0r + jc*32 + uu*4);
                a += w00[u].x*hv.x + w00[u].y*hv.y + w00[u].z*hv.z + w00[u].w*hv.w;
            }
            a += R1+R2+R3+R4+R5+R6+R7;
            a += dpp_get<0xB1>(a); a += dpp_get<0x4E>(a);   // quad reduce
            const float2 wih0 = wih_s[row00];
            const float hv0 = fast_tanh(a + xt.x*wih0.x + xt.y*wih0.y);
            if (jc == 0) H0[(t+1)&1][row00] = hv0;
            const float2 fw0 = fcw_s[row00];
            float o0 = (jc == 0) ? hv0*fw0.x : 0.f;
            float o1 = (jc == 0) ? hv0*fw0.y : 0.f;
            o0 += dpp_get<0x111>(o0); o1 += dpp_get<0x111>(o1);
            o0 += dpp_get<0x112>(o0); o1 += dpp_get<0x112>(o1);
            o0 += dpp_get<0x114>(o0); o1 += dpp_get<0x114>(o1);
            o0 += dpp_get<0x118>(o0); o1 += dpp_get<0x118>(o1);
            o0 += dpp_get<0x142>(o0); o1 += dpp_get<0x142>(o1);
            o0 += dpp_get<0x143>(o0); o1 += dpp_get<0x143>(o1);
            if (lane == 63) OpM0[t&1][wave] = make_float2(o0, o1);
        }

        // ---- modules 1..A: cheap row updates from Sp2s (even & t==0) ----
        if (A >= 1) {
            const int nrows = (A+1)*MS;
            {
                const int g = MS + tid;
                if (g < nrows) {
                    const int r = g >> 7, il = g & (MS-1);
                    float sc[8];
                    #pragma unroll
                    for (int c = 1; c < 8; ++c)
                        sc[c] = Sp2s[c*(c+1)/2 + ((c < r) ? c : r)][il];
                    const float2 wih2 = wih_s[g];
                    float pre = xt.x*wih2.x + xt.y*wih2.y;
                    #pragma unroll
                    for (int c = 1; c < 8; ++c) pre += (c >= r) ? sc[c] : 0.f;
                    const float hv = fast_tanh(pre);
                    h_s[g] = hv;
                    const float2 fw = fcw_s[g];
                    float o0 = hv*fw.x, o1 = hv*fw.y;
                    o0 += dpp_get<0x111>(o0); o1 += dpp_get<0x111>(o1);
                    o0 += dpp_get<0x112>(o0); o1 += dpp_get<0x112>(o1);
                    o0 += dpp_get<0x114>(o0); o1 += dpp_get<0x114>(o1);
                    o0 += dpp_get<0x118>(o0); o1 += dpp_get<0x118>(o1);
                    o0 += dpp_get<0x142>(o0); o1 += dpp_get<0x142>(o1);
                    o0 += dpp_get<0x143>(o0); o1 += dpp_get<0x143>(o1);
                    if (lane == 63) OpHiN[2 + wave] = make_float2(o0, o1);
                }
            }
            {
                const int g = 5*MS + tid;
                if (g < nrows) {
                    const int r = g >> 7, il = g & (MS-1);
                    float sc[8];
                    #pragma unroll
                    for (int c = 1; c < 8; ++c)
                        sc[c] = Sp2s[c*(c+1)/2 + ((c < r) ? c : r)][il];
                    const float2 wih2 = wih_s[g];
                    float pre = xt.x*wih2.x + xt.y*wih2.y;
                    #pragma unroll
                    for (int c = 1; c < 8; ++c) pre += (c >= r) ? sc[c] : 0.f;
                    const float hv = fast_tanh(pre);
                    h_s[g] = hv;
                    const float2 fw = fcw_s[g];
                    float o0 = hv*fw.x, o1 = hv*fw.y;
                    o0 += dpp_get<0x111>(o0); o1 += dpp_get<0x111>(o1);
                    o0 += dpp_get<0x112>(o0); o1 += dpp_get<0x112>(o1);
                    o0 += dpp_get<0x114>(o0); o1 += dpp_get<0x114>(o1);
                    o0 += dpp_get<0x118>(o0); o1 += dpp_get<0x118>(o1);
                    o0 += dpp_get<0x142>(o0); o1 += dpp_get<0x142>(o1);
                    o0 += dpp_get<0x143>(o0); o1 += dpp_get<0x143>(o1);
                    if (lane == 63) OpHiN[10 + wave] = make_float2(o0, o1);
                }
            }
        }

        // ---- finalize out[t-1]: promote OpHiN (odd regions), sum, store ----
        if (t > 0 && tid == 0) {
            const int tp = t - 1;
            if (ap >= 1) {
                for (int k = 2; k <= 2*ap+1; ++k) OpHi[k] = OpHiN[k];
            }
            float o0 = fb0, o1 = fb1;
            #pragma unroll
            for (int w = 0; w < 8; ++w) { o0 += OpM0[tp&1][w].x; o1 += OpM0[tp&1][w].y; }
            #pragma unroll
            for (int k = 2; k < 16; ++k) { o0 += OpHi[k].x; o1 += OpHi[k].y; }
            *(float2*)(outb + 2*tp) = make_float2(o0, o1);
        }

        __syncthreads();            // the ONE barrier per step
    }

    if (tid == 0) {                 // out[511]
        float o0 = fb0, o1 = fb1;
        #pragma unroll
        for (int w = 0; w < 8; ++w) { o0 += OpM0[1][w].x; o1 += OpM0[1][w].y; }
        #pragma unroll
        for (int k = 2; k < 16; ++k) { o0 += OpHi[k].x; o1 += OpHi[k].y; }
        *(float2*)(outb + 2*(Tsz-1)) = make_float2(o0, o1);
    }
}

// ---------------------------------------------------------------------------
extern "C" void kernel_launch(void* const* d_in, const int* in_sizes, int n_in,
                              void* d_out, int out_size, void* d_ws, size_t ws_size,
                              hipStream_t stream) {
    const float* x     = (const float*)d_in[0];
    const float* W_ih  = (const float*)d_in[1];
    const float* W_hh  = (const float*)d_in[2];
    const float* fc_w  = (const float*)d_in[3];
    const float* fc_b  = (const float*)d_in[4];
    const float* enc_w = (const float*)d_in[5];
    float* outp = (float*)d_out;
    float*  WB0 = (float*)d_ws;                          // 64 KB
    __half* WBr = (__half*)((char*)d_ws + 65536);        // 35*16384*2 B

    retile_whh<<<36, 256, 0, stream>>>(W_hh, WB0, WBr);
    cwrnn_kernel<<<Bsz, NT, 0, stream>>>(x, W_ih, fc_w, fc_b, enc_w, WB0, WBr, outp);
}